// Round 1
// baseline (2643.848 us; speedup 1.0000x reference)
//
#include <hip/hip_runtime.h>
#include <hip/hip_bf16.h>
#include <math.h>

// Problem dims
#define BB 64      // batch
#define OO 64      // out_n
#define II 1152    // in_n
#define DD 32      // out_d
#define KK 16      // in_d

#define NS 16      // i-splits for the big passes
#define IC (II/NS) // 72 i per block

__device__ __forceinline__ float dot16(const float4* __restrict__ wp,
                                       float4 a0, float4 a1, float4 a2, float4 a3) {
  float4 w0 = wp[0], w1 = wp[1], w2 = wp[2], w3 = wp[3];
  float d = w0.x * a0.x;
  d = fmaf(w0.y, a0.y, d); d = fmaf(w0.z, a0.z, d); d = fmaf(w0.w, a0.w, d);
  d = fmaf(w1.x, a1.x, d); d = fmaf(w1.y, a1.y, d); d = fmaf(w1.z, a1.z, d); d = fmaf(w1.w, a1.w, d);
  d = fmaf(w2.x, a2.x, d); d = fmaf(w2.y, a2.y, d); d = fmaf(w2.z, a2.z, d); d = fmaf(w2.w, a2.w, d);
  d = fmaf(w3.x, a3.x, d); d = fmaf(w3.y, a3.y, d); d = fmaf(w3.z, a3.z, d); d = fmaf(w3.w, a3.w, d);
  return d;
}

// s[b,o,d] += sum_{i in chunk} c[o,i,b] * (W[o,i] . x[b,i])   (c==nullptr -> 1)
__global__ __launch_bounds__(256) void ksum_kernel(
    const float* __restrict__ x, const float* __restrict__ weight,
    const float* __restrict__ c, float* __restrict__ s) {
  const int o = blockIdx.y;
  const int i0 = blockIdx.x * IC;
  const int b = threadIdx.x & 63;
  const int wv = __builtin_amdgcn_readfirstlane(threadIdx.x >> 6);

  float acc[DD];
#pragma unroll
  for (int d = 0; d < DD; ++d) acc[d] = 0.f;

  for (int t = 0; t < IC / 4; ++t) {
    const int i = i0 + wv + 4 * t;
    const float4* xp = reinterpret_cast<const float4*>(x + ((size_t)b * II + i) * KK);
    float4 x0 = xp[0], x1 = xp[1], x2 = xp[2], x3 = xp[3];
    const float4* wp = reinterpret_cast<const float4*>(
        weight + ((size_t)o * II + i) * (size_t)(DD * KK));
    float cc = 1.0f;
    if (c) cc = c[((size_t)o * II + i) * BB + b];
#pragma unroll
    for (int d = 0; d < DD; ++d) {
      float dot = dot16(wp + 4 * d, x0, x1, x2, x3);
      acc[d] = fmaf(cc, dot, acc[d]);
    }
  }
  float* sp = s + ((size_t)b * OO + o) * DD;
#pragma unroll
  for (int d = 0; d < DD; ++d) atomicAdd(sp + d, acc[d]);
}

// blog[o,i,b] = sum_d Vsum[b,o,d] * (W[o,i] . x[b,i])_d
__global__ __launch_bounds__(256) void kblog_kernel(
    const float* __restrict__ x, const float* __restrict__ weight,
    const float* __restrict__ vsum, float* __restrict__ blog) {
  const int o = blockIdx.y;
  const int i0 = blockIdx.x * IC;
  const int b = threadIdx.x & 63;
  const int wv = __builtin_amdgcn_readfirstlane(threadIdx.x >> 6);

  float vs[DD];
  const float* vp = vsum + ((size_t)b * OO + o) * DD;
#pragma unroll
  for (int d = 0; d < DD; ++d) vs[d] = vp[d];

  for (int t = 0; t < IC / 4; ++t) {
    const int i = i0 + wv + 4 * t;
    const float4* xp = reinterpret_cast<const float4*>(x + ((size_t)b * II + i) * KK);
    float4 x0 = xp[0], x1 = xp[1], x2 = xp[2], x3 = xp[3];
    const float4* wp = reinterpret_cast<const float4*>(
        weight + ((size_t)o * II + i) * (size_t)(DD * KK));
    float bl = 0.f;
#pragma unroll
    for (int d = 0; d < DD; ++d) {
      float dot = dot16(wp + 4 * d, x0, x1, x2, x3);
      bl = fmaf(vs[d], dot, bl);
    }
    blog[((size_t)o * II + i) * BB + b] = bl;
  }
}

// softmax over o (in place). thread <-> (i,b). grid: II*BB/256 = 288 blocks.
__global__ __launch_bounds__(256) void ksm_kernel(float* __restrict__ blog) {
  const size_t idx = (size_t)blockIdx.x * 256 + threadIdx.x;
  const int b = (int)(idx & 63);
  const int i = (int)(idx >> 6);
  float vals[OO];
  float m = -1e30f;
#pragma unroll
  for (int o = 0; o < OO; ++o) {
    vals[o] = blog[((size_t)o * II + i) * BB + b];
    m = fmaxf(m, vals[o]);
  }
  float sum = 0.f;
#pragma unroll
  for (int o = 0; o < OO; ++o) {
    vals[o] = expf(vals[o] - m);
    sum += vals[o];
  }
  const float r = 1.0f / sum;
#pragma unroll
  for (int o = 0; o < OO; ++o)
    blog[((size_t)o * II + i) * BB + b] = vals[o] * r;
}

// squash rows of s (scaled by cscale); dst = (add ? dst + v : v)
// thread <-> (row, d): 4096 rows x 32 lanes. grid 512 blocks.
__global__ __launch_bounds__(256) void ksq_kernel(
    const float* __restrict__ s_in, float* __restrict__ dst, float cscale, int add) {
  const int tid = blockIdx.x * 256 + threadIdx.x;
  const int d = tid & 31;
  const size_t row = (size_t)(tid >> 5);
  float v = s_in[row * DD + d] * cscale;
  float n2 = v * v;
#pragma unroll
  for (int m = 1; m < 32; m <<= 1) n2 += __shfl_xor(n2, m, 64);
  const float norm = sqrtf(n2);
  const float scale = n2 / ((1.0f + n2) * (norm + 1e-8f));
  const float outv = scale * v;
  if (add) dst[row * DD + d] += outv;
  else     dst[row * DD + d] = outv;
}

extern "C" void kernel_launch(void* const* d_in, const int* in_sizes, int n_in,
                              void* d_out, int out_size, void* d_ws, size_t ws_size,
                              hipStream_t stream) {
  const float* x = (const float*)d_in[0];
  const float* w = (const float*)d_in[1];
  float* out = (float*)d_out;

  char* ws = (char*)d_ws;
  const size_t blog_bytes = (size_t)II * BB * OO * 4;      // 18,874,368
  const size_t so_bytes = (size_t)BB * OO * DD * 4;        // 524,288
  float* blog = (float*)ws;
  float* vsum = (float*)(ws + blog_bytes);
  float* s    = (float*)(ws + blog_bytes + so_bytes);

  dim3 gS(NS, OO), bS(256);
  const int g_sm = (II * BB) / 256;        // 288
  const int g_sq = (BB * OO * DD) / 256;   // 512

  // iter 0: c uniform = 1/64  -> v0, vsum = v0
  hipMemsetAsync(s, 0, so_bytes, stream);
  ksum_kernel<<<gS, bS, 0, stream>>>(x, w, nullptr, s);
  ksq_kernel<<<g_sq, 256, 0, stream>>>(s, vsum, 1.0f / 64.0f, 0);

  // iter 1: blog = vsum . x_hat ; c1 = softmax ; s1 ; vsum += v1
  kblog_kernel<<<gS, bS, 0, stream>>>(x, w, vsum, blog);
  ksm_kernel<<<g_sm, 256, 0, stream>>>(blog);
  hipMemsetAsync(s, 0, so_bytes, stream);
  ksum_kernel<<<gS, bS, 0, stream>>>(x, w, blog, s);
  ksq_kernel<<<g_sq, 256, 0, stream>>>(s, vsum, 1.0f, 1);

  // iter 2: blog2 = (v0+v1) . x_hat ; c2 ; s2 ; out = squash(s2)
  kblog_kernel<<<gS, bS, 0, stream>>>(x, w, vsum, blog);
  ksm_kernel<<<g_sm, 256, 0, stream>>>(blog);
  hipMemsetAsync(s, 0, so_bytes, stream);
  ksum_kernel<<<gS, bS, 0, stream>>>(x, w, blog, s);
  ksq_kernel<<<g_sq, 256, 0, stream>>>(s, out, 1.0f, 0);
}

// Round 2
// 1635.730 us; speedup vs baseline: 1.6163x; 1.6163x over previous
//
#include <hip/hip_runtime.h>
#include <hip/hip_bf16.h>
#include <math.h>

// Problem dims
#define BB 64      // batch
#define OO 64      // out_n
#define II 1152    // in_n
#define DD 32      // out_d
#define KK 16      // in_d

#define NS 32      // i-splits for the big passes
#define IC (II/NS) // 36 i per block

__device__ __forceinline__ float dot16(const float4* __restrict__ wp,
                                       float4 a0, float4 a1, float4 a2, float4 a3) {
  float4 w0 = wp[0], w1 = wp[1], w2 = wp[2], w3 = wp[3];
  float d = w0.x * a0.x;
  d = fmaf(w0.y, a0.y, d); d = fmaf(w0.z, a0.z, d); d = fmaf(w0.w, a0.w, d);
  d = fmaf(w1.x, a1.x, d); d = fmaf(w1.y, a1.y, d); d = fmaf(w1.z, a1.z, d); d = fmaf(w1.w, a1.w, d);
  d = fmaf(w2.x, a2.x, d); d = fmaf(w2.y, a2.y, d); d = fmaf(w2.z, a2.z, d); d = fmaf(w2.w, a2.w, d);
  d = fmaf(w3.x, a3.x, d); d = fmaf(w3.y, a3.y, d); d = fmaf(w3.z, a3.z, d); d = fmaf(w3.w, a3.w, d);
  return d;
}

// s[b,o,d] += sum_{i in chunk} c[o,i,b] * (W[o,i] . x[b,i])_d   (c==nullptr -> 1)
// wave wv handles d in [8*wv, 8*wv+8) for ALL i in the chunk -> acc[8] per thread.
__global__ __launch_bounds__(256) void ksum_kernel(
    const float* __restrict__ x, const float* __restrict__ weight,
    const float* __restrict__ c, float* __restrict__ s) {
  const int o = blockIdx.y;
  const int i0 = blockIdx.x * IC;
  const int b = threadIdx.x & 63;
  const int wv = __builtin_amdgcn_readfirstlane(threadIdx.x >> 6);
  const int d0 = wv * 8;

  float acc0 = 0.f, acc1 = 0.f, acc2 = 0.f, acc3 = 0.f;
  float acc4 = 0.f, acc5 = 0.f, acc6 = 0.f, acc7 = 0.f;

  for (int t = 0; t < IC; ++t) {
    const int i = i0 + t;
    const float4* xp = reinterpret_cast<const float4*>(x + ((size_t)b * II + i) * KK);
    float4 x0 = xp[0], x1 = xp[1], x2 = xp[2], x3 = xp[3];
    const float4* wp = reinterpret_cast<const float4*>(
        weight + ((size_t)o * II + i) * (size_t)(DD * KK)) + 4 * d0;
    float cc = 1.0f;
    if (c) cc = c[((size_t)o * II + i) * BB + b];
    acc0 = fmaf(cc, dot16(wp + 0,  x0, x1, x2, x3), acc0);
    acc1 = fmaf(cc, dot16(wp + 4,  x0, x1, x2, x3), acc1);
    acc2 = fmaf(cc, dot16(wp + 8,  x0, x1, x2, x3), acc2);
    acc3 = fmaf(cc, dot16(wp + 12, x0, x1, x2, x3), acc3);
    acc4 = fmaf(cc, dot16(wp + 16, x0, x1, x2, x3), acc4);
    acc5 = fmaf(cc, dot16(wp + 20, x0, x1, x2, x3), acc5);
    acc6 = fmaf(cc, dot16(wp + 24, x0, x1, x2, x3), acc6);
    acc7 = fmaf(cc, dot16(wp + 28, x0, x1, x2, x3), acc7);
  }
  float* sp = s + ((size_t)b * OO + o) * DD + d0;
  atomicAdd(sp + 0, acc0); atomicAdd(sp + 1, acc1);
  atomicAdd(sp + 2, acc2); atomicAdd(sp + 3, acc3);
  atomicAdd(sp + 4, acc4); atomicAdd(sp + 5, acc5);
  atomicAdd(sp + 6, acc6); atomicAdd(sp + 7, acc7);
}

// blog[o,i,b] = sum_d Vsum[b,o,d] * (W[o,i] . x[b,i])_d
__global__ __launch_bounds__(256) void kblog_kernel(
    const float* __restrict__ x, const float* __restrict__ weight,
    const float* __restrict__ vsum, float* __restrict__ blog) {
  const int o = blockIdx.y;
  const int i0 = blockIdx.x * IC;
  const int b = threadIdx.x & 63;
  const int wv = __builtin_amdgcn_readfirstlane(threadIdx.x >> 6);

  float vs[DD];
  const float* vp = vsum + ((size_t)b * OO + o) * DD;
#pragma unroll
  for (int d = 0; d < DD; ++d) vs[d] = vp[d];

  for (int t = 0; t < IC / 4; ++t) {
    const int i = i0 + wv + 4 * t;
    const float4* xp = reinterpret_cast<const float4*>(x + ((size_t)b * II + i) * KK);
    float4 x0 = xp[0], x1 = xp[1], x2 = xp[2], x3 = xp[3];
    const float4* wp = reinterpret_cast<const float4*>(
        weight + ((size_t)o * II + i) * (size_t)(DD * KK));
    float bl = 0.f;
#pragma unroll
    for (int d = 0; d < DD; ++d) {
      float dot = dot16(wp + 4 * d, x0, x1, x2, x3);
      bl = fmaf(vs[d], dot, bl);
    }
    blog[((size_t)o * II + i) * BB + b] = bl;
  }
}

// softmax over o (in place). thread <-> (i,b). grid: II*BB/256 = 288 blocks.
__global__ __launch_bounds__(256) void ksm_kernel(float* __restrict__ blog) {
  const size_t idx = (size_t)blockIdx.x * 256 + threadIdx.x;
  const int b = (int)(idx & 63);
  const int i = (int)(idx >> 6);
  float vals[OO];
  float m = -1e30f;
#pragma unroll
  for (int o = 0; o < OO; ++o) {
    vals[o] = blog[((size_t)o * II + i) * BB + b];
    m = fmaxf(m, vals[o]);
  }
  float sum = 0.f;
#pragma unroll
  for (int o = 0; o < OO; ++o) {
    vals[o] = expf(vals[o] - m);
    sum += vals[o];
  }
  const float r = 1.0f / sum;
#pragma unroll
  for (int o = 0; o < OO; ++o)
    blog[((size_t)o * II + i) * BB + b] = vals[o] * r;
}

// squash rows of s (scaled by cscale); dst = (add ? dst + v : v)
// thread <-> (row, d): 4096 rows x 32 lanes. grid 512 blocks.
__global__ __launch_bounds__(256) void ksq_kernel(
    const float* __restrict__ s_in, float* __restrict__ dst, float cscale, int add) {
  const int tid = blockIdx.x * 256 + threadIdx.x;
  const int d = tid & 31;
  const size_t row = (size_t)(tid >> 5);
  float v = s_in[row * DD + d] * cscale;
  float n2 = v * v;
#pragma unroll
  for (int m = 1; m < 32; m <<= 1) n2 += __shfl_xor(n2, m, 64);
  const float norm = sqrtf(n2);
  const float scale = n2 / ((1.0f + n2) * (norm + 1e-8f));
  const float outv = scale * v;
  if (add) dst[row * DD + d] += outv;
  else     dst[row * DD + d] = outv;
}

extern "C" void kernel_launch(void* const* d_in, const int* in_sizes, int n_in,
                              void* d_out, int out_size, void* d_ws, size_t ws_size,
                              hipStream_t stream) {
  const float* x = (const float*)d_in[0];
  const float* w = (const float*)d_in[1];
  float* out = (float*)d_out;

  char* ws = (char*)d_ws;
  const size_t blog_bytes = (size_t)II * BB * OO * 4;      // 18,874,368
  const size_t so_bytes = (size_t)BB * OO * DD * 4;        // 524,288
  float* blog = (float*)ws;
  float* vsum = (float*)(ws + blog_bytes);
  float* s    = (float*)(ws + blog_bytes + so_bytes);

  dim3 gS(NS, OO), bS(256);
  dim3 gB(8, OO);                          // kblog keeps wave-per-i layout: 8*4 waves cover 36? no:
  // kblog uses IC/4 loop with wv stride 4: grid.x must satisfy IC%4==0; IC=36 ok, grid.x = NS
  const int g_sm = (II * BB) / 256;        // 288
  const int g_sq = (BB * OO * DD) / 256;   // 512

  // iter 0: c uniform = 1/64  -> v0, vsum = v0
  hipMemsetAsync(s, 0, so_bytes, stream);
  ksum_kernel<<<gS, bS, 0, stream>>>(x, w, nullptr, s);
  ksq_kernel<<<g_sq, 256, 0, stream>>>(s, vsum, 1.0f / 64.0f, 0);

  // iter 1: blog = vsum . x_hat ; c1 = softmax ; s1 ; vsum += v1
  kblog_kernel<<<gS, bS, 0, stream>>>(x, w, vsum, blog);
  ksm_kernel<<<g_sm, 256, 0, stream>>>(blog);
  hipMemsetAsync(s, 0, so_bytes, stream);
  ksum_kernel<<<gS, bS, 0, stream>>>(x, w, blog, s);
  ksq_kernel<<<g_sq, 256, 0, stream>>>(s, vsum, 1.0f, 1);

  // iter 2: blog2 = (v0+v1) . x_hat ; c2 ; s2 ; out = squash(s2)
  kblog_kernel<<<gS, bS, 0, stream>>>(x, w, vsum, blog);
  ksm_kernel<<<g_sm, 256, 0, stream>>>(blog);
  hipMemsetAsync(s, 0, so_bytes, stream);
  ksum_kernel<<<gS, bS, 0, stream>>>(x, w, blog, s);
  ksq_kernel<<<g_sq, 256, 0, stream>>>(s, out, 1.0f, 0);
}

// Round 3
// 689.365 us; speedup vs baseline: 3.8352x; 2.3728x over previous
//
#include <hip/hip_runtime.h>
#include <hip/hip_bf16.h>
#include <math.h>

// Problem dims
#define BB 64      // batch
#define OO 64      // out_n
#define II 1152    // in_n
#define DD 32      // out_d
#define KK 16      // in_d

#define NS 16      // i-splits for the big passes
#define IC (II/NS) // 72 i per block

__device__ __forceinline__ float dot16(const float4* __restrict__ wp,
                                       float4 a0, float4 a1, float4 a2, float4 a3) {
  float4 w0 = wp[0], w1 = wp[1], w2 = wp[2], w3 = wp[3];
  float d = w0.x * a0.x;
  d = fmaf(w0.y, a0.y, d); d = fmaf(w0.z, a0.z, d); d = fmaf(w0.w, a0.w, d);
  d = fmaf(w1.x, a1.x, d); d = fmaf(w1.y, a1.y, d); d = fmaf(w1.z, a1.z, d); d = fmaf(w1.w, a1.w, d);
  d = fmaf(w2.x, a2.x, d); d = fmaf(w2.y, a2.y, d); d = fmaf(w2.z, a2.z, d); d = fmaf(w2.w, a2.w, d);
  d = fmaf(w3.x, a3.x, d); d = fmaf(w3.y, a3.y, d); d = fmaf(w3.z, a3.z, d); d = fmaf(w3.w, a3.w, d);
  return d;
}

// partial[split][o][d][b] = sum_{i in chunk} c[o,i,b] * (W[o,i] . x[b,i])_d
// wave wv handles d in [8*wv, 8*wv+8). NO atomics.
__global__ __launch_bounds__(256) void ksum_kernel(
    const float* __restrict__ x, const float* __restrict__ weight,
    const float* __restrict__ c, float* __restrict__ partial) {
  const int o = blockIdx.y;
  const int split = blockIdx.x;
  const int i0 = split * IC;
  const int b = threadIdx.x & 63;
  const int wv = __builtin_amdgcn_readfirstlane(threadIdx.x >> 6);
  const int d0 = wv * 8;

  float acc0 = 0.f, acc1 = 0.f, acc2 = 0.f, acc3 = 0.f;
  float acc4 = 0.f, acc5 = 0.f, acc6 = 0.f, acc7 = 0.f;

#pragma unroll 2
  for (int t = 0; t < IC; ++t) {
    const int i = i0 + t;
    const float4* xp = reinterpret_cast<const float4*>(x + ((size_t)b * II + i) * KK);
    float4 x0 = xp[0], x1 = xp[1], x2 = xp[2], x3 = xp[3];
    const float4* wp = reinterpret_cast<const float4*>(
        weight + ((size_t)o * II + i) * (size_t)(DD * KK)) + 4 * d0;
    float cc = 1.0f;
    if (c) cc = c[((size_t)o * II + i) * BB + b];
    acc0 = fmaf(cc, dot16(wp + 0,  x0, x1, x2, x3), acc0);
    acc1 = fmaf(cc, dot16(wp + 4,  x0, x1, x2, x3), acc1);
    acc2 = fmaf(cc, dot16(wp + 8,  x0, x1, x2, x3), acc2);
    acc3 = fmaf(cc, dot16(wp + 12, x0, x1, x2, x3), acc3);
    acc4 = fmaf(cc, dot16(wp + 16, x0, x1, x2, x3), acc4);
    acc5 = fmaf(cc, dot16(wp + 20, x0, x1, x2, x3), acc5);
    acc6 = fmaf(cc, dot16(wp + 24, x0, x1, x2, x3), acc6);
    acc7 = fmaf(cc, dot16(wp + 28, x0, x1, x2, x3), acc7);
  }
  // coalesced: lane=b contiguous
  float* pp = partial + (((size_t)split * OO + o) * DD + d0) * BB + b;
  pp[0 * BB] = acc0; pp[1 * BB] = acc1; pp[2 * BB] = acc2; pp[3 * BB] = acc3;
  pp[4 * BB] = acc4; pp[5 * BB] = acc5; pp[6 * BB] = acc6; pp[7 * BB] = acc7;
}

// s[b,o,d] = sum_split partial[split][o][d][b].  grid: 131072/256 = 512 blocks.
__global__ __launch_bounds__(256) void kreduce_kernel(
    const float* __restrict__ partial, float* __restrict__ s) {
  const int tid = blockIdx.x * 256 + threadIdx.x;   // maps (o,d,b)
  const int o = tid / (DD * BB);
  const int r = tid % (DD * BB);
  const int d = r / BB;
  const int b = r % BB;
  float sum = 0.f;
#pragma unroll
  for (int sp = 0; sp < NS; ++sp)
    sum += partial[(((size_t)sp * OO + o) * DD + d) * BB + b];
  s[((size_t)b * OO + o) * DD + d] = sum;
}

// blog[o,i,b] = sum_d Vsum[b,o,d] * (W[o,i] . x[b,i])_d
__global__ __launch_bounds__(256) void kblog_kernel(
    const float* __restrict__ x, const float* __restrict__ weight,
    const float* __restrict__ vsum, float* __restrict__ blog) {
  const int o = blockIdx.y;
  const int i0 = blockIdx.x * IC;
  const int b = threadIdx.x & 63;
  const int wv = __builtin_amdgcn_readfirstlane(threadIdx.x >> 6);

  float vs[DD];
  const float* vp = vsum + ((size_t)b * OO + o) * DD;
#pragma unroll
  for (int d = 0; d < DD; ++d) vs[d] = vp[d];

  for (int t = 0; t < IC / 4; ++t) {
    const int i = i0 + wv + 4 * t;
    const float4* xp = reinterpret_cast<const float4*>(x + ((size_t)b * II + i) * KK);
    float4 x0 = xp[0], x1 = xp[1], x2 = xp[2], x3 = xp[3];
    const float4* wp = reinterpret_cast<const float4*>(
        weight + ((size_t)o * II + i) * (size_t)(DD * KK));
    float bl = 0.f;
#pragma unroll
    for (int d = 0; d < DD; ++d) {
      float dot = dot16(wp + 4 * d, x0, x1, x2, x3);
      bl = fmaf(vs[d], dot, bl);
    }
    blog[((size_t)o * II + i) * BB + b] = bl;
  }
}

// softmax over o (in place). thread <-> (i,b). grid: II*BB/256 = 288 blocks.
__global__ __launch_bounds__(256) void ksm_kernel(float* __restrict__ blog) {
  const size_t idx = (size_t)blockIdx.x * 256 + threadIdx.x;
  const int b = (int)(idx & 63);
  const int i = (int)(idx >> 6);
  float vals[OO];
  float m = -1e30f;
#pragma unroll
  for (int o = 0; o < OO; ++o) {
    vals[o] = blog[((size_t)o * II + i) * BB + b];
    m = fmaxf(m, vals[o]);
  }
  float sum = 0.f;
#pragma unroll
  for (int o = 0; o < OO; ++o) {
    vals[o] = expf(vals[o] - m);
    sum += vals[o];
  }
  const float r = 1.0f / sum;
#pragma unroll
  for (int o = 0; o < OO; ++o)
    blog[((size_t)o * II + i) * BB + b] = vals[o] * r;
}

// squash rows of s (scaled by cscale); dst = (add ? dst + v : v)
__global__ __launch_bounds__(256) void ksq_kernel(
    const float* __restrict__ s_in, float* __restrict__ dst, float cscale, int add) {
  const int tid = blockIdx.x * 256 + threadIdx.x;
  const int d = tid & 31;
  const size_t row = (size_t)(tid >> 5);
  float v = s_in[row * DD + d] * cscale;
  float n2 = v * v;
#pragma unroll
  for (int m = 1; m < 32; m <<= 1) n2 += __shfl_xor(n2, m, 64);
  const float norm = sqrtf(n2);
  const float scale = n2 / ((1.0f + n2) * (norm + 1e-8f));
  const float outv = scale * v;
  if (add) dst[row * DD + d] += outv;
  else     dst[row * DD + d] = outv;
}

extern "C" void kernel_launch(void* const* d_in, const int* in_sizes, int n_in,
                              void* d_out, int out_size, void* d_ws, size_t ws_size,
                              hipStream_t stream) {
  const float* x = (const float*)d_in[0];
  const float* w = (const float*)d_in[1];
  float* out = (float*)d_out;

  char* ws = (char*)d_ws;
  const size_t blog_bytes = (size_t)II * BB * OO * 4;        // 18,874,368
  const size_t so_bytes = (size_t)BB * OO * DD * 4;          // 524,288
  const size_t part_bytes = (size_t)NS * OO * DD * BB * 4;   // 8,388,608
  float* blog = (float*)ws;
  float* vsum = (float*)(ws + blog_bytes);
  float* s    = (float*)(ws + blog_bytes + so_bytes);
  float* part = (float*)(ws + blog_bytes + 2 * so_bytes);

  dim3 gS(NS, OO), bS(256);
  const int g_sm = (II * BB) / 256;        // 288
  const int g_sq = (BB * OO * DD) / 256;   // 512
  const int g_rd = (OO * DD * BB) / 256;   // 512

  // iter 0: c uniform = 1/64  -> v0, vsum = v0
  ksum_kernel<<<gS, bS, 0, stream>>>(x, w, nullptr, part);
  kreduce_kernel<<<g_rd, 256, 0, stream>>>(part, s);
  ksq_kernel<<<g_sq, 256, 0, stream>>>(s, vsum, 1.0f / 64.0f, 0);

  // iter 1: blog = vsum . x_hat ; c1 = softmax ; s1 ; vsum += v1
  kblog_kernel<<<gS, bS, 0, stream>>>(x, w, vsum, blog);
  ksm_kernel<<<g_sm, 256, 0, stream>>>(blog);
  ksum_kernel<<<gS, bS, 0, stream>>>(x, w, blog, part);
  kreduce_kernel<<<g_rd, 256, 0, stream>>>(part, s);
  ksq_kernel<<<g_sq, 256, 0, stream>>>(s, vsum, 1.0f, 1);

  // iter 2: blog2 = (v0+v1) . x_hat ; c2 ; s2 ; out = squash(s2)
  kblog_kernel<<<gS, bS, 0, stream>>>(x, w, vsum, blog);
  ksm_kernel<<<g_sm, 256, 0, stream>>>(blog);
  ksum_kernel<<<gS, bS, 0, stream>>>(x, w, blog, part);
  kreduce_kernel<<<g_rd, 256, 0, stream>>>(part, s);
  ksq_kernel<<<g_sq, 256, 0, stream>>>(s, out, 1.0f, 0);
}

// Round 4
// 212.629 us; speedup vs baseline: 12.4341x; 3.2421x over previous
//
#include <hip/hip_runtime.h>
#include <hip/hip_bf16.h>
#include <math.h>

// Problem dims
#define BB 64      // batch
#define OO 64      // out_n
#define II 1152    // in_n
#define DD 32      // out_d
#define KK 16      // in_d

#define NS2 32       // i-splits for heavy passes
#define IC2 (II/NS2) // 36 i per wave

typedef float f32x16 __attribute__((ext_vector_type(16)));
typedef short bf16x8 __attribute__((ext_vector_type(8)));

// ---------------------------------------------------------------------------
// Split fp32 -> (hi RNE bf16, lo trunc bf16) helper (as bit patterns in short)
__device__ __forceinline__ void split_bf16(float v, short& hs, short& ls) {
  unsigned u = __float_as_uint(v);
  unsigned r = (u + 0x7FFFu + ((u >> 16) & 1u)) & 0xFFFF0000u;  // RNE bf16 of v
  float hi = __uint_as_float(r);
  float lo = v - hi;
  hs = (short)(r >> 16);
  ls = (short)(__float_as_uint(lo) >> 16);  // trunc bf16 of residual
}

// ---------------------------------------------------------------------------
// Prefab x into MFMA B-fragments (hi/lo bf16), pure x (no c).
// Frag layout: yh[((i*2+T)*64 + lane)*8 + j] = bf16hi( x[b=32T+(lane&31), i, k=8*(lane>>5)+j] )
__global__ __launch_bounds__(256) void kxfrag_kernel(
    const float* __restrict__ x, short* __restrict__ yh, short* __restrict__ yl) {
  const int t = blockIdx.x * 256 + threadIdx.x;  // (i, lane)
  const int l = t & 63;
  const int i = t >> 6;
  const int k0 = 8 * (l >> 5);
  const int ln31 = l & 31;
#pragma unroll
  for (int T = 0; T < 2; ++T) {
    const int b = T * 32 + ln31;
    const float* xp = x + ((size_t)b * II + i) * KK + k0;
    float4 a = *(const float4*)xp;
    float4 c4 = *(const float4*)(xp + 4);
    float v[8] = {a.x, a.y, a.z, a.w, c4.x, c4.y, c4.z, c4.w};
    bf16x8 hs, ls;
#pragma unroll
    for (int j = 0; j < 8; ++j) {
      short h, lo;
      split_bf16(v[j], h, lo);
      hs[j] = h; ls[j] = lo;
    }
    *(bf16x8*)(yh + ((size_t)i * 2 + T) * 512 + l * 8) = hs;
    *(bf16x8*)(yl + ((size_t)i * 2 + T) * 512 + l * 8) = ls;
  }
}

// ---------------------------------------------------------------------------
// Heavy pass. MODE 0 (ksum): partial[sp][o][d][b] = sum_i c[o,i,b]*xhat[d,b]
//            MODE 1 (kblog): blog[o,i,b] = sum_d vsumT[o,d,b]*xhat[d,b]
// Block = 4 waves, wave wv -> o = blockIdx.y*4+wv; all waves share i-chunk sp.
// Per (o,i): xhat(32d x 64b) via 6 x mfma_f32_32x32x16_bf16 (split-bf16, 3 terms x 2 b-tiles).
template <int MODE>
__global__ __launch_bounds__(256) void kmain_kernel(
    const float* __restrict__ weight,
    const short* __restrict__ yh, const short* __restrict__ yl,
    const float* __restrict__ c,       // MODE 0: routing coeffs or null (-> 1/64)
    const float* __restrict__ vsumT,   // MODE 1: [o][d][b]
    float* __restrict__ outp) {        // MODE 0: partial, MODE 1: blog
  const int l = threadIdx.x & 63;
  const int wv = threadIdx.x >> 6;
  const int o = blockIdx.y * 4 + wv;
  const int sp = blockIdx.x;
  const int i0 = sp * IC2;
  const int h = l >> 5;
  const int ln31 = l & 31;

  f32x16 zero = {};
  f32x16 acc0 = {}, acc1 = {};
  float vs0[16], vs1[16];
  if (MODE == 1) {
#pragma unroll
    for (int r = 0; r < 16; ++r) {
      const int row = (r & 3) + 8 * (r >> 2) + 4 * h;
      vs0[r] = vsumT[((size_t)o * DD + row) * BB + ln31];
      vs1[r] = vsumT[((size_t)o * DD + row) * BB + 32 + ln31];
    }
  }

  // per-lane A-fragment base: W[o, i, d=ln31, k=8h..8h+8)
  const float* wbase = weight + (size_t)o * II * 512 + ln31 * 16 + h * 8;

  for (int t = 0; t < IC2; ++t) {
    const int i = i0 + t;
    // --- load W frag (fp32) and split to hi/lo bf16 ---
    const float* wp = wbase + (size_t)i * 512;
    float4 wa = *(const float4*)wp;
    float4 wb = *(const float4*)(wp + 4);
    float wf[8] = {wa.x, wa.y, wa.z, wa.w, wb.x, wb.y, wb.z, wb.w};
    bf16x8 whf, wlf;
#pragma unroll
    for (int j = 0; j < 8; ++j) {
      short hs, ls;
      split_bf16(wf[j], hs, ls);
      whf[j] = hs; wlf[j] = ls;
    }
    // --- Y frags (prefab) ---
    const bf16x8 yh0 = *(const bf16x8*)(yh + ((size_t)i * 2 + 0) * 512 + l * 8);
    const bf16x8 yh1 = *(const bf16x8*)(yh + ((size_t)i * 2 + 1) * 512 + l * 8);
    const bf16x8 yl0 = *(const bf16x8*)(yl + ((size_t)i * 2 + 0) * 512 + l * 8);
    const bf16x8 yl1 = *(const bf16x8*)(yl + ((size_t)i * 2 + 1) * 512 + l * 8);

    // --- xhat tiles: 3-term split-bf16 product, C chained from persistent zero ---
    f32x16 t0 = __builtin_amdgcn_mfma_f32_32x32x16_bf16(whf, yl0, zero, 0, 0, 0);
    t0 = __builtin_amdgcn_mfma_f32_32x32x16_bf16(wlf, yh0, t0, 0, 0, 0);
    t0 = __builtin_amdgcn_mfma_f32_32x32x16_bf16(whf, yh0, t0, 0, 0, 0);
    f32x16 t1 = __builtin_amdgcn_mfma_f32_32x32x16_bf16(whf, yl1, zero, 0, 0, 0);
    t1 = __builtin_amdgcn_mfma_f32_32x32x16_bf16(wlf, yh1, t1, 0, 0, 0);
    t1 = __builtin_amdgcn_mfma_f32_32x32x16_bf16(whf, yh1, t1, 0, 0, 0);

    if (MODE == 0) {
      float cc0 = 0.015625f, cc1 = 0.015625f;
      if (c) {
        cc0 = c[((size_t)o * II + i) * BB + ln31];
        cc1 = c[((size_t)o * II + i) * BB + 32 + ln31];
      }
#pragma unroll
      for (int r = 0; r < 16; ++r) {
        acc0[r] = fmaf(cc0, t0[r], acc0[r]);
        acc1[r] = fmaf(cc1, t1[r], acc1[r]);
      }
    } else {
      float p0 = 0.f, p1 = 0.f;
#pragma unroll
      for (int r = 0; r < 16; ++r) {
        p0 = fmaf(vs0[r], t0[r], p0);
        p1 = fmaf(vs1[r], t1[r], p1);
      }
      p0 += __shfl_xor(p0, 32, 64);
      p1 += __shfl_xor(p1, 32, 64);
      outp[((size_t)o * II + i) * BB + l] = (l < 32) ? p0 : p1;
    }
  }

  if (MODE == 0) {
#pragma unroll
    for (int r = 0; r < 16; ++r) {
      const int row = (r & 3) + 8 * (r >> 2) + 4 * h;
      outp[((size_t)(sp * OO + o) * DD + row) * BB + ln31] = acc0[r];
      outp[((size_t)(sp * OO + o) * DD + row) * BB + 32 + ln31] = acc1[r];
    }
  }
}

// ---------------------------------------------------------------------------
// s[b,o,d] = sum_split partial[split][o][d][b].  grid: 131072/256 = 512 blocks.
__global__ __launch_bounds__(256) void kreduce_kernel(
    const float* __restrict__ partial, float* __restrict__ s) {
  const int tid = blockIdx.x * 256 + threadIdx.x;   // maps (o,d,b)
  const int o = tid / (DD * BB);
  const int r = tid % (DD * BB);
  const int d = r / BB;
  const int b = r % BB;
  float sum = 0.f;
#pragma unroll
  for (int sp = 0; sp < NS2; ++sp)
    sum += partial[(((size_t)sp * OO + o) * DD + d) * BB + b];
  s[((size_t)b * OO + o) * DD + d] = sum;
}

// ---------------------------------------------------------------------------
// softmax over o (in place). thread <-> (i,b). grid: II*BB/256 = 288 blocks.
__global__ __launch_bounds__(256) void ksm_kernel(float* __restrict__ blog) {
  const size_t idx = (size_t)blockIdx.x * 256 + threadIdx.x;
  const int b = (int)(idx & 63);
  const int i = (int)(idx >> 6);
  float vals[OO];
  float m = -1e30f;
#pragma unroll
  for (int o = 0; o < OO; ++o) {
    vals[o] = blog[((size_t)o * II + i) * BB + b];
    m = fmaxf(m, vals[o]);
  }
  float sum = 0.f;
#pragma unroll
  for (int o = 0; o < OO; ++o) {
    vals[o] = expf(vals[o] - m);
    sum += vals[o];
  }
  const float r = 1.0f / sum;
#pragma unroll
  for (int o = 0; o < OO; ++o)
    blog[((size_t)o * II + i) * BB + b] = vals[o] * r;
}

// ---------------------------------------------------------------------------
// squash rows of s; dst = (add ? dst + v : v); optionally write vsumT[o][d][b].
__global__ __launch_bounds__(256) void ksq_kernel(
    const float* __restrict__ s_in, float* __restrict__ dst,
    float* __restrict__ vsumT, int add) {
  const int tid = blockIdx.x * 256 + threadIdx.x;
  const int d = tid & 31;
  const size_t row = (size_t)(tid >> 5);   // row = b*64 + o
  float v = s_in[row * DD + d];
  float n2 = v * v;
#pragma unroll
  for (int m = 1; m < 32; m <<= 1) n2 += __shfl_xor(n2, m, 64);
  const float norm = sqrtf(n2);
  const float scale = n2 / ((1.0f + n2) * (norm + 1e-8f));
  float outv = scale * v;
  if (add) outv += dst[row * DD + d];
  dst[row * DD + d] = outv;
  if (vsumT) {
    const int b = (int)(row >> 6);
    const int o = (int)(row & 63);
    vsumT[((size_t)o * DD + d) * BB + b] = outv;
  }
}

// ---------------------------------------------------------------------------
extern "C" void kernel_launch(void* const* d_in, const int* in_sizes, int n_in,
                              void* d_out, int out_size, void* d_ws, size_t ws_size,
                              hipStream_t stream) {
  const float* x = (const float*)d_in[0];
  const float* w = (const float*)d_in[1];
  float* out = (float*)d_out;

  char* ws = (char*)d_ws;
  const size_t blog_bytes = (size_t)OO * II * BB * 4;        // 18,874,368
  const size_t part_bytes = (size_t)NS2 * OO * DD * BB * 4;  // 16,777,216
  const size_t yf_bytes   = (size_t)II * 2 * 64 * 8 * 2;     //  2,359,296
  const size_t so_bytes   = (size_t)BB * OO * DD * 4;        //    524,288

  float* blog  = (float*)ws;                      ws += blog_bytes;
  float* part  = (float*)ws;                      ws += part_bytes;
  short* yh    = (short*)ws;                      ws += yf_bytes;
  short* yl    = (short*)ws;                      ws += yf_bytes;
  float* vsum  = (float*)ws;                      ws += so_bytes;
  float* vsumT = (float*)ws;                      ws += so_bytes;
  float* s     = (float*)ws;                      ws += so_bytes;

  dim3 gM(NS2, OO / 4), bM(256);
  const int g_xf = (II * 64) / 256;        // 288
  const int g_sm = (II * BB) / 256;        // 288
  const int g_sq = (BB * OO * DD) / 256;   // 512
  const int g_rd = (OO * DD * BB) / 256;   // 512

  // prefab x B-fragments (hi/lo)
  kxfrag_kernel<<<g_xf, 256, 0, stream>>>(x, yh, yl);

  // iter 0: c uniform = 1/64 -> v0; vsum = v0 (+vsumT)
  kmain_kernel<0><<<gM, bM, 0, stream>>>(w, yh, yl, nullptr, nullptr, part);
  kreduce_kernel<<<g_rd, 256, 0, stream>>>(part, s);
  ksq_kernel<<<g_sq, 256, 0, stream>>>(s, vsum, vsumT, 0);

  // iter 1: blog = vsum . xhat ; c1 = softmax ; s1 ; vsum += v1 (+vsumT)
  kmain_kernel<1><<<gM, bM, 0, stream>>>(w, yh, yl, nullptr, vsumT, blog);
  ksm_kernel<<<g_sm, 256, 0, stream>>>(blog);
  kmain_kernel<0><<<gM, bM, 0, stream>>>(w, yh, yl, blog, nullptr, part);
  kreduce_kernel<<<g_rd, 256, 0, stream>>>(part, s);
  ksq_kernel<<<g_sq, 256, 0, stream>>>(s, vsum, vsumT, 1);

  // iter 2: blog2 = (v0+v1) . xhat ; c2 ; s2 ; out = squash(s2)
  kmain_kernel<1><<<gM, bM, 0, stream>>>(w, yh, yl, nullptr, vsumT, blog);
  ksm_kernel<<<g_sm, 256, 0, stream>>>(blog);
  kmain_kernel<0><<<gM, bM, 0, stream>>>(w, yh, yl, blog, nullptr, part);
  kreduce_kernel<<<g_rd, 256, 0, stream>>>(part, s);
  ksq_kernel<<<g_sq, 256, 0, stream>>>(s, out, nullptr, 0);
}

// Round 5
// 205.088 us; speedup vs baseline: 12.8913x; 1.0368x over previous
//
#include <hip/hip_runtime.h>
#include <hip/hip_bf16.h>
#include <math.h>

// Problem dims
#define BB 64      // batch
#define OO 64      // out_n
#define II 1152    // in_n
#define DD 32      // out_d
#define KK 16      // in_d

// ksum: grid (SPS, OO); block = 4 waves all on SAME o, each wave 18 i.
#define SPS 16
#define ICS (II/SPS)     // 72 i per block
#define ICW (ICS/4)      // 18 i per wave
// kblog: grid (SPB, OO/4); block = 4 waves on 4 o's, same 18-i chunk.
#define SPB 64
#define ICB (II/SPB)     // 18 i per block

typedef float f32x16 __attribute__((ext_vector_type(16)));
typedef short bf16x8 __attribute__((ext_vector_type(8)));

// ---------------------------------------------------------------------------
__device__ __forceinline__ void split_bf16(float v, short& hs, short& ls) {
  unsigned u = __float_as_uint(v);
  unsigned r = (u + 0x7FFFu + ((u >> 16) & 1u)) & 0xFFFF0000u;  // RNE bf16 of v
  float hi = __uint_as_float(r);
  float lo = v - hi;
  hs = (short)(r >> 16);
  ls = (short)(__float_as_uint(lo) >> 16);  // trunc bf16 of residual
}

// ---------------------------------------------------------------------------
// Prefab x into MFMA B-fragments (hi/lo bf16).
// yh[((i*2+T)*64 + lane)*8 + j] = bf16hi( x[b=32T+(lane&31), i, k=8*(lane>>5)+j] )
__global__ __launch_bounds__(256) void kxfrag_kernel(
    const float* __restrict__ x, short* __restrict__ yh, short* __restrict__ yl) {
  const int t = blockIdx.x * 256 + threadIdx.x;  // (i, lane)
  const int l = t & 63;
  const int i = t >> 6;
  const int k0 = 8 * (l >> 5);
  const int ln31 = l & 31;
#pragma unroll
  for (int T = 0; T < 2; ++T) {
    const int b = T * 32 + ln31;
    const float* xp = x + ((size_t)b * II + i) * KK + k0;
    float4 a = *(const float4*)xp;
    float4 c4 = *(const float4*)(xp + 4);
    float v[8] = {a.x, a.y, a.z, a.w, c4.x, c4.y, c4.z, c4.w};
    bf16x8 hs, ls;
#pragma unroll
    for (int j = 0; j < 8; ++j) {
      short h, lo;
      split_bf16(v[j], h, lo);
      hs[j] = h; ls[j] = lo;
    }
    *(bf16x8*)(yh + ((size_t)i * 2 + T) * 512 + l * 8) = hs;
    *(bf16x8*)(yl + ((size_t)i * 2 + T) * 512 + l * 8) = ls;
  }
}

// ---------------------------------------------------------------------------
// partial[sp][o][d][b] = sum_{i in chunk sp} c[o,i,b]*xhat[d,b]  (c null -> 1/64)
// Block: 4 waves, SAME o, wave wv covers i = sp*72 + wv*18 + [0,18). LDS-reduced.
__global__ __launch_bounds__(256) void ksum_kernel(
    const float* __restrict__ weight,
    const short* __restrict__ yh, const short* __restrict__ yl,
    const float* __restrict__ c, float* __restrict__ partial) {
  const int l = threadIdx.x & 63;
  const int wv = threadIdx.x >> 6;
  const int o = blockIdx.y;
  const int sp = blockIdx.x;
  const int h = l >> 5;
  const int ln31 = l & 31;

  __shared__ float red[4][DD * BB];

  f32x16 zero = {};
  f32x16 acc0 = {}, acc1 = {};

  const float* wbase = weight + (size_t)o * II * 512 + ln31 * 16 + h * 8;
  const int i0 = sp * ICS + wv * ICW;

#pragma unroll 2
  for (int t = 0; t < ICW; ++t) {
    const int i = i0 + t;
    const float* wp = wbase + (size_t)i * 512;
    float4 wa = *(const float4*)wp;
    float4 wb = *(const float4*)(wp + 4);
    float wf[8] = {wa.x, wa.y, wa.z, wa.w, wb.x, wb.y, wb.z, wb.w};
    bf16x8 whf, wlf;
#pragma unroll
    for (int j = 0; j < 8; ++j) {
      short hs, ls;
      split_bf16(wf[j], hs, ls);
      whf[j] = hs; wlf[j] = ls;
    }
    const bf16x8 yh0 = *(const bf16x8*)(yh + ((size_t)i * 2 + 0) * 512 + l * 8);
    const bf16x8 yh1 = *(const bf16x8*)(yh + ((size_t)i * 2 + 1) * 512 + l * 8);
    const bf16x8 yl0 = *(const bf16x8*)(yl + ((size_t)i * 2 + 0) * 512 + l * 8);
    const bf16x8 yl1 = *(const bf16x8*)(yl + ((size_t)i * 2 + 1) * 512 + l * 8);

    f32x16 t0 = __builtin_amdgcn_mfma_f32_32x32x16_bf16(whf, yl0, zero, 0, 0, 0);
    t0 = __builtin_amdgcn_mfma_f32_32x32x16_bf16(wlf, yh0, t0, 0, 0, 0);
    t0 = __builtin_amdgcn_mfma_f32_32x32x16_bf16(whf, yh0, t0, 0, 0, 0);
    f32x16 t1 = __builtin_amdgcn_mfma_f32_32x32x16_bf16(whf, yl1, zero, 0, 0, 0);
    t1 = __builtin_amdgcn_mfma_f32_32x32x16_bf16(wlf, yh1, t1, 0, 0, 0);
    t1 = __builtin_amdgcn_mfma_f32_32x32x16_bf16(whf, yh1, t1, 0, 0, 0);

    float cc0 = 0.015625f, cc1 = 0.015625f;
    if (c) {
      cc0 = c[((size_t)o * II + i) * BB + ln31];
      cc1 = c[((size_t)o * II + i) * BB + 32 + ln31];
    }
#pragma unroll
    for (int r = 0; r < 16; ++r) {
      acc0[r] = fmaf(cc0, t0[r], acc0[r]);
      acc1[r] = fmaf(cc1, t1[r], acc1[r]);
    }
  }

  // stash wave accumulators to LDS
#pragma unroll
  for (int r = 0; r < 16; ++r) {
    const int row = (r & 3) + 8 * (r >> 2) + 4 * h;
    red[wv][row * BB + ln31] = acc0[r];
    red[wv][row * BB + 32 + ln31] = acc1[r];
  }
  __syncthreads();

  // tree-reduce 4 waves -> partial[sp][o][.]
  float* pp = partial + ((size_t)sp * OO + o) * (DD * BB);
  for (int e = threadIdx.x; e < DD * BB; e += 256)
    pp[e] = red[0][e] + red[1][e] + red[2][e] + red[3][e];
}

// ---------------------------------------------------------------------------
// blog[o,i,b] = sum_d vsumT[o,d,b]*xhat[d,b]
// Block: 4 waves on o = blockIdx.y*4+wv, shared 18-i chunk sp = blockIdx.x.
__global__ __launch_bounds__(256) void kblog_kernel(
    const float* __restrict__ weight,
    const short* __restrict__ yh, const short* __restrict__ yl,
    const float* __restrict__ vsumT, float* __restrict__ blog) {
  const int l = threadIdx.x & 63;
  const int wv = threadIdx.x >> 6;
  const int o = blockIdx.y * 4 + wv;
  const int sp = blockIdx.x;
  const int i0 = sp * ICB;
  const int h = l >> 5;
  const int ln31 = l & 31;

  f32x16 zero = {};
  float vs0[16], vs1[16];
#pragma unroll
  for (int r = 0; r < 16; ++r) {
    const int row = (r & 3) + 8 * (r >> 2) + 4 * h;
    vs0[r] = vsumT[((size_t)o * DD + row) * BB + ln31];
    vs1[r] = vsumT[((size_t)o * DD + row) * BB + 32 + ln31];
  }

  const float* wbase = weight + (size_t)o * II * 512 + ln31 * 16 + h * 8;

#pragma unroll 2
  for (int t = 0; t < ICB; ++t) {
    const int i = i0 + t;
    const float* wp = wbase + (size_t)i * 512;
    float4 wa = *(const float4*)wp;
    float4 wb = *(const float4*)(wp + 4);
    float wf[8] = {wa.x, wa.y, wa.z, wa.w, wb.x, wb.y, wb.z, wb.w};
    bf16x8 whf, wlf;
#pragma unroll
    for (int j = 0; j < 8; ++j) {
      short hs, ls;
      split_bf16(wf[j], hs, ls);
      whf[j] = hs; wlf[j] = ls;
    }
    const bf16x8 yh0 = *(const bf16x8*)(yh + ((size_t)i * 2 + 0) * 512 + l * 8);
    const bf16x8 yh1 = *(const bf16x8*)(yh + ((size_t)i * 2 + 1) * 512 + l * 8);
    const bf16x8 yl0 = *(const bf16x8*)(yl + ((size_t)i * 2 + 0) * 512 + l * 8);
    const bf16x8 yl1 = *(const bf16x8*)(yl + ((size_t)i * 2 + 1) * 512 + l * 8);

    f32x16 t0 = __builtin_amdgcn_mfma_f32_32x32x16_bf16(whf, yl0, zero, 0, 0, 0);
    t0 = __builtin_amdgcn_mfma_f32_32x32x16_bf16(wlf, yh0, t0, 0, 0, 0);
    t0 = __builtin_amdgcn_mfma_f32_32x32x16_bf16(whf, yh0, t0, 0, 0, 0);
    f32x16 t1 = __builtin_amdgcn_mfma_f32_32x32x16_bf16(whf, yl1, zero, 0, 0, 0);
    t1 = __builtin_amdgcn_mfma_f32_32x32x16_bf16(wlf, yh1, t1, 0, 0, 0);
    t1 = __builtin_amdgcn_mfma_f32_32x32x16_bf16(whf, yh1, t1, 0, 0, 0);

    float p0 = 0.f, p1 = 0.f;
#pragma unroll
    for (int r = 0; r < 16; ++r) {
      p0 = fmaf(vs0[r], t0[r], p0);
      p1 = fmaf(vs1[r], t1[r], p1);
    }
    p0 += __shfl_xor(p0, 32, 64);
    p1 += __shfl_xor(p1, 32, 64);
    blog[((size_t)o * II + i) * BB + l] = (l < 32) ? p0 : p1;
  }
}

// ---------------------------------------------------------------------------
// s[b,o,d] = sum_sp partial[sp][o][d][b].  grid: 131072/256 = 512 blocks.
__global__ __launch_bounds__(256) void kreduce_kernel(
    const float* __restrict__ partial, float* __restrict__ s) {
  const int tid = blockIdx.x * 256 + threadIdx.x;   // maps (o,d,b)
  const int o = tid / (DD * BB);
  const int r = tid % (DD * BB);
  const int d = r / BB;
  const int b = r % BB;
  float sum = 0.f;
#pragma unroll
  for (int sp = 0; sp < SPS; ++sp)
    sum += partial[(((size_t)sp * OO + o) * DD + d) * BB + b];
  s[((size_t)b * OO + o) * DD + d] = sum;
}

// ---------------------------------------------------------------------------
// softmax over o (in place). thread <-> (i,b). grid: II*BB/256 = 288 blocks.
__global__ __launch_bounds__(256) void ksm_kernel(float* __restrict__ blog) {
  const size_t idx = (size_t)blockIdx.x * 256 + threadIdx.x;
  const int b = (int)(idx & 63);
  const int i = (int)(idx >> 6);
  float vals[OO];
  float m = -1e30f;
#pragma unroll
  for (int o = 0; o < OO; ++o) {
    vals[o] = blog[((size_t)o * II + i) * BB + b];
    m = fmaxf(m, vals[o]);
  }
  float sum = 0.f;
#pragma unroll
  for (int o = 0; o < OO; ++o) {
    vals[o] = expf(vals[o] - m);
    sum += vals[o];
  }
  const float r = 1.0f / sum;
#pragma unroll
  for (int o = 0; o < OO; ++o)
    blog[((size_t)o * II + i) * BB + b] = vals[o] * r;
}

// ---------------------------------------------------------------------------
// squash rows of s; dst = (add ? dst + v : v); optionally write vsumT[o][d][b].
__global__ __launch_bounds__(256) void ksq_kernel(
    const float* __restrict__ s_in, float* __restrict__ dst,
    float* __restrict__ vsumT, int add) {
  const int tid = blockIdx.x * 256 + threadIdx.x;
  const int d = tid & 31;
  const size_t row = (size_t)(tid >> 5);   // row = b*64 + o
  float v = s_in[row * DD + d];
  float n2 = v * v;
#pragma unroll
  for (int m = 1; m < 32; m <<= 1) n2 += __shfl_xor(n2, m, 64);
  const float norm = sqrtf(n2);
  const float scale = n2 / ((1.0f + n2) * (norm + 1e-8f));
  float outv = scale * v;
  if (add) outv += dst[row * DD + d];
  dst[row * DD + d] = outv;
  if (vsumT) {
    const int b = (int)(row >> 6);
    const int o = (int)(row & 63);
    vsumT[((size_t)o * DD + d) * BB + b] = outv;
  }
}

// ---------------------------------------------------------------------------
extern "C" void kernel_launch(void* const* d_in, const int* in_sizes, int n_in,
                              void* d_out, int out_size, void* d_ws, size_t ws_size,
                              hipStream_t stream) {
  const float* x = (const float*)d_in[0];
  const float* w = (const float*)d_in[1];
  float* out = (float*)d_out;

  char* ws = (char*)d_ws;
  const size_t blog_bytes = (size_t)OO * II * BB * 4;        // 18,874,368
  const size_t part_bytes = (size_t)SPS * OO * DD * BB * 4;  //  8,388,608
  const size_t yf_bytes   = (size_t)II * 2 * 64 * 8 * 2;     //  2,359,296
  const size_t so_bytes   = (size_t)BB * OO * DD * 4;        //    524,288

  float* blog  = (float*)ws;                      ws += blog_bytes;
  float* part  = (float*)ws;                      ws += part_bytes;
  short* yh    = (short*)ws;                      ws += yf_bytes;
  short* yl    = (short*)ws;                      ws += yf_bytes;
  float* vsum  = (float*)ws;                      ws += so_bytes;
  float* vsumT = (float*)ws;                      ws += so_bytes;
  float* s     = (float*)ws;                      ws += so_bytes;

  dim3 gSum(SPS, OO), gBlog(SPB, OO / 4), bM(256);
  const int g_xf = (II * 64) / 256;        // 288
  const int g_sm = (II * BB) / 256;        // 288
  const int g_sq = (BB * OO * DD) / 256;   // 512
  const int g_rd = (OO * DD * BB) / 256;   // 512

  // prefab x B-fragments (hi/lo)
  kxfrag_kernel<<<g_xf, 256, 0, stream>>>(x, yh, yl);

  // iter 0: c uniform = 1/64 -> v0; vsum = v0 (+vsumT)
  ksum_kernel<<<gSum, bM, 0, stream>>>(w, yh, yl, nullptr, part);
  kreduce_kernel<<<g_rd, 256, 0, stream>>>(part, s);
  ksq_kernel<<<g_sq, 256, 0, stream>>>(s, vsum, vsumT, 0);

  // iter 1: blog = vsum . xhat ; c1 = softmax ; s1 ; vsum += v1 (+vsumT)
  kblog_kernel<<<gBlog, bM, 0, stream>>>(w, yh, yl, vsumT, blog);
  ksm_kernel<<<g_sm, 256, 0, stream>>>(blog);
  ksum_kernel<<<gSum, bM, 0, stream>>>(w, yh, yl, blog, part);
  kreduce_kernel<<<g_rd, 256, 0, stream>>>(part, s);
  ksq_kernel<<<g_sq, 256, 0, stream>>>(s, vsum, vsumT, 1);

  // iter 2: blog2 = (v0+v1) . xhat ; c2 ; s2 ; out = squash(s2)
  kblog_kernel<<<gBlog, bM, 0, stream>>>(w, yh, yl, vsumT, blog);
  ksm_kernel<<<g_sm, 256, 0, stream>>>(blog);
  ksum_kernel<<<gSum, bM, 0, stream>>>(w, yh, yl, blog, part);
  kreduce_kernel<<<g_rd, 256, 0, stream>>>(part, s);
  ksq_kernel<<<g_sq, 256, 0, stream>>>(s, out, nullptr, 0);
}

// Round 6
// 203.353 us; speedup vs baseline: 13.0013x; 1.0085x over previous
//
#include <hip/hip_runtime.h>
#include <hip/hip_bf16.h>
#include <math.h>

// Problem dims
#define BB 64      // batch
#define OO 64      // out_n
#define II 1152    // in_n
#define DD 32      // out_d
#define KK 16      // in_d

// ksum: grid (SPS, OO); block = 4 waves all on SAME o, each wave 18 i.
#define SPS 16
#define ICS (II/SPS)     // 72 i per block
#define ICW (ICS/4)      // 18 i per wave
// kblog: grid (SPB, OO/4); block = 4 waves on 4 o's, same 18-i chunk.
#define SPB 64
#define ICB (II/SPB)     // 18 i per block

typedef float f32x16 __attribute__((ext_vector_type(16)));
typedef short bf16x8 __attribute__((ext_vector_type(8)));

// ---------------------------------------------------------------------------
__device__ __forceinline__ void split_bf16(float v, short& hs, short& ls) {
  unsigned u = __float_as_uint(v);
  unsigned r = (u + 0x7FFFu + ((u >> 16) & 1u)) & 0xFFFF0000u;  // RNE bf16 of v
  float hi = __uint_as_float(r);
  float lo = v - hi;
  hs = (short)(r >> 16);
  ls = (short)(__float_as_uint(lo) >> 16);  // trunc bf16 of residual
}

// ---------------------------------------------------------------------------
// Prefab x into MFMA B-fragments (hi/lo bf16).
// yh[(i*1024) + T*512 + lane*8 + j] = bf16hi( x[b=32T+(lane&31), i, k=8*(lane>>5)+j] )
__global__ __launch_bounds__(256) void kxfrag_kernel(
    const float* __restrict__ x, short* __restrict__ yh, short* __restrict__ yl) {
  const int t = blockIdx.x * 256 + threadIdx.x;  // (i, lane)
  const int l = t & 63;
  const int i = t >> 6;
  const int k0 = 8 * (l >> 5);
  const int ln31 = l & 31;
#pragma unroll
  for (int T = 0; T < 2; ++T) {
    const int b = T * 32 + ln31;
    const float* xp = x + ((size_t)b * II + i) * KK + k0;
    float4 a = *(const float4*)xp;
    float4 c4 = *(const float4*)(xp + 4);
    float v[8] = {a.x, a.y, a.z, a.w, c4.x, c4.y, c4.z, c4.w};
    bf16x8 hs, ls;
#pragma unroll
    for (int j = 0; j < 8; ++j) {
      short h, lo;
      split_bf16(v[j], h, lo);
      hs[j] = h; ls[j] = lo;
    }
    *(bf16x8*)(yh + (size_t)i * 1024 + T * 512 + l * 8) = hs;
    *(bf16x8*)(yl + (size_t)i * 1024 + T * 512 + l * 8) = ls;
  }
}

// ---------------------------------------------------------------------------
// partial[sp][o][d][b] = sum_{i in chunk sp} c[o,i,b]*xhat[d,b]
// HAS_C=0 -> c = 1/64. HAS_C=1 -> c = exp(blog - m) * rinv  (softmax on the fly)
// Block: 4 waves, SAME o, wave wv covers i = sp*72 + wv*18 + [0,18). LDS-reduced.
template <int HAS_C>
__global__ __launch_bounds__(256) void ksum_kernel(
    const float* __restrict__ weight,
    const short* __restrict__ yh, const short* __restrict__ yl,
    const float* __restrict__ blog, const float2* __restrict__ sm,
    float* __restrict__ partial) {
  const int l = threadIdx.x & 63;
  const int wv = threadIdx.x >> 6;
  const int o = blockIdx.y;
  const int sp = blockIdx.x;
  const int h = l >> 5;
  const int ln31 = l & 31;

  __shared__ float red[4][DD * BB];

  f32x16 zero = {};
  f32x16 acc0 = {}, acc1 = {};

  const float* wbase = weight + (size_t)o * II * 512 + ln31 * 16 + h * 8;
  const int i0 = sp * ICS + wv * ICW;

  float4 Awa, Awb, Bwa, Bwb;
  bf16x8 Ayh0, Ayh1, Ayl0, Ayl1, Byh0, Byh1, Byl0, Byl1;
  float Abl0 = 0.f, Abl1 = 0.f, Bbl0 = 0.f, Bbl1 = 0.f;
  float2 Asm0 = {}, Asm1 = {}, Bsm0 = {}, Bsm1 = {};

#define SLOAD(P, ii)                                                          \
  {                                                                           \
    const float* wp = wbase + (size_t)(ii) * 512;                             \
    P##wa = *(const float4*)wp;                                               \
    P##wb = *(const float4*)(wp + 4);                                         \
    const short* yhb = yh + (size_t)(ii) * 1024 + l * 8;                      \
    const short* ylb = yl + (size_t)(ii) * 1024 + l * 8;                      \
    P##yh0 = *(const bf16x8*)(yhb);                                           \
    P##yh1 = *(const bf16x8*)(yhb + 512);                                     \
    P##yl0 = *(const bf16x8*)(ylb);                                           \
    P##yl1 = *(const bf16x8*)(ylb + 512);                                     \
    if (HAS_C) {                                                              \
      P##bl0 = blog[((size_t)o * II + (ii)) * BB + ln31];                     \
      P##bl1 = blog[((size_t)o * II + (ii)) * BB + 32 + ln31];                \
      P##sm0 = sm[(size_t)(ii) * BB + ln31];                                  \
      P##sm1 = sm[(size_t)(ii) * BB + 32 + ln31];                             \
    }                                                                         \
  }

#define SCOMP(P)                                                              \
  {                                                                           \
    float wf[8] = {P##wa.x, P##wa.y, P##wa.z, P##wa.w,                        \
                   P##wb.x, P##wb.y, P##wb.z, P##wb.w};                       \
    bf16x8 whf, wlf;                                                          \
    _Pragma("unroll") for (int j = 0; j < 8; ++j) {                           \
      short hs, ls;                                                           \
      split_bf16(wf[j], hs, ls);                                              \
      whf[j] = hs; wlf[j] = ls;                                               \
    }                                                                         \
    f32x16 t0 = __builtin_amdgcn_mfma_f32_32x32x16_bf16(whf, P##yl0, zero, 0, 0, 0); \
    t0 = __builtin_amdgcn_mfma_f32_32x32x16_bf16(wlf, P##yh0, t0, 0, 0, 0);   \
    t0 = __builtin_amdgcn_mfma_f32_32x32x16_bf16(whf, P##yh0, t0, 0, 0, 0);   \
    f32x16 t1 = __builtin_amdgcn_mfma_f32_32x32x16_bf16(whf, P##yl1, zero, 0, 0, 0); \
    t1 = __builtin_amdgcn_mfma_f32_32x32x16_bf16(wlf, P##yh1, t1, 0, 0, 0);   \
    t1 = __builtin_amdgcn_mfma_f32_32x32x16_bf16(whf, P##yh1, t1, 0, 0, 0);   \
    float cc0 = 0.015625f, cc1 = 0.015625f;                                   \
    if (HAS_C) {                                                              \
      cc0 = __expf(P##bl0 - P##sm0.x) * P##sm0.y;                             \
      cc1 = __expf(P##bl1 - P##sm1.x) * P##sm1.y;                             \
    }                                                                         \
    _Pragma("unroll") for (int r = 0; r < 16; ++r) {                          \
      acc0[r] = fmaf(cc0, t0[r], acc0[r]);                                    \
      acc1[r] = fmaf(cc1, t1[r], acc1[r]);                                    \
    }                                                                         \
  }

  SLOAD(A, i0);
  SLOAD(B, i0 + 1);
#pragma unroll 1
  for (int t = 0; t < ICW - 2; t += 2) {
    SCOMP(A);
    SLOAD(A, i0 + t + 2);
    SCOMP(B);
    SLOAD(B, i0 + t + 3);
  }
  SCOMP(A);
  SCOMP(B);
#undef SLOAD
#undef SCOMP

  // stash wave accumulators to LDS
#pragma unroll
  for (int r = 0; r < 16; ++r) {
    const int row = (r & 3) + 8 * (r >> 2) + 4 * h;
    red[wv][row * BB + ln31] = acc0[r];
    red[wv][row * BB + 32 + ln31] = acc1[r];
  }
  __syncthreads();

  // tree-reduce 4 waves -> partial[sp][o][.]
  float* pp = partial + ((size_t)sp * OO + o) * (DD * BB);
  for (int e = threadIdx.x; e < DD * BB; e += 256)
    pp[e] = red[0][e] + red[1][e] + red[2][e] + red[3][e];
}

// ---------------------------------------------------------------------------
// blog[o,i,b] = sum_d vsumT[o,d,b]*xhat[d,b]
// Block: 4 waves on o = blockIdx.y*4+wv, shared 18-i chunk sp = blockIdx.x.
__global__ __launch_bounds__(256) void kblog_kernel(
    const float* __restrict__ weight,
    const short* __restrict__ yh, const short* __restrict__ yl,
    const float* __restrict__ vsumT, float* __restrict__ blog) {
  const int l = threadIdx.x & 63;
  const int wv = threadIdx.x >> 6;
  const int o = blockIdx.y * 4 + wv;
  const int sp = blockIdx.x;
  const int i0 = sp * ICB;
  const int h = l >> 5;
  const int ln31 = l & 31;

  f32x16 zero = {};
  float vs0[16], vs1[16];
#pragma unroll
  for (int r = 0; r < 16; ++r) {
    const int row = (r & 3) + 8 * (r >> 2) + 4 * h;
    vs0[r] = vsumT[((size_t)o * DD + row) * BB + ln31];
    vs1[r] = vsumT[((size_t)o * DD + row) * BB + 32 + ln31];
  }

  const float* wbase = weight + (size_t)o * II * 512 + ln31 * 16 + h * 8;

  float4 Awa, Awb, Bwa, Bwb;
  bf16x8 Ayh0, Ayh1, Ayl0, Ayl1, Byh0, Byh1, Byl0, Byl1;

#define BLOAD(P, ii)                                                          \
  {                                                                           \
    const float* wp = wbase + (size_t)(ii) * 512;                             \
    P##wa = *(const float4*)wp;                                               \
    P##wb = *(const float4*)(wp + 4);                                         \
    const short* yhb = yh + (size_t)(ii) * 1024 + l * 8;                      \
    const short* ylb = yl + (size_t)(ii) * 1024 + l * 8;                      \
    P##yh0 = *(const bf16x8*)(yhb);                                           \
    P##yh1 = *(const bf16x8*)(yhb + 512);                                     \
    P##yl0 = *(const bf16x8*)(ylb);                                           \
    P##yl1 = *(const bf16x8*)(ylb + 512);                                     \
  }

#define BCOMP(P, ii)                                                          \
  {                                                                           \
    float wf[8] = {P##wa.x, P##wa.y, P##wa.z, P##wa.w,                        \
                   P##wb.x, P##wb.y, P##wb.z, P##wb.w};                       \
    bf16x8 whf, wlf;                                                          \
    _Pragma("unroll") for (int j = 0; j < 8; ++j) {                           \
      short hs, ls;                                                           \
      split_bf16(wf[j], hs, ls);                                              \
      whf[j] = hs; wlf[j] = ls;                                               \
    }                                                                         \
    f32x16 t0 = __builtin_amdgcn_mfma_f32_32x32x16_bf16(whf, P##yl0, zero, 0, 0, 0); \
    t0 = __builtin_amdgcn_mfma_f32_32x32x16_bf16(wlf, P##yh0, t0, 0, 0, 0);   \
    t0 = __builtin_amdgcn_mfma_f32_32x32x16_bf16(whf, P##yh0, t0, 0, 0, 0);   \
    f32x16 t1 = __builtin_amdgcn_mfma_f32_32x32x16_bf16(whf, P##yl1, zero, 0, 0, 0); \
    t1 = __builtin_amdgcn_mfma_f32_32x32x16_bf16(wlf, P##yh1, t1, 0, 0, 0);   \
    t1 = __builtin_amdgcn_mfma_f32_32x32x16_bf16(whf, P##yh1, t1, 0, 0, 0);   \
    float p0 = 0.f, p1 = 0.f;                                                 \
    _Pragma("unroll") for (int r = 0; r < 16; ++r) {                          \
      p0 = fmaf(vs0[r], t0[r], p0);                                           \
      p1 = fmaf(vs1[r], t1[r], p1);                                           \
    }                                                                         \
    p0 += __shfl_xor(p0, 32, 64);                                             \
    p1 += __shfl_xor(p1, 32, 64);                                             \
    blog[((size_t)o * II + (ii)) * BB + l] = (l < 32) ? p0 : p1;              \
  }

  BLOAD(A, i0);
  BLOAD(B, i0 + 1);
#pragma unroll 1
  for (int t = 0; t < ICB - 2; t += 2) {
    BCOMP(A, i0 + t);
    BLOAD(A, i0 + t + 2);
    BCOMP(B, i0 + t + 1);
    BLOAD(B, i0 + t + 3);
  }
  BCOMP(A, i0 + ICB - 2);
  BCOMP(B, i0 + ICB - 1);
#undef BLOAD
#undef BCOMP
}

// ---------------------------------------------------------------------------
// sm[i*BB+b] = (max_o blog, 1/sum_o exp(blog-max)).  grid: II*BB/256 = 288.
__global__ __launch_bounds__(256) void kdenom_kernel(
    const float* __restrict__ blog, float2* __restrict__ sm) {
  const size_t idx = (size_t)blockIdx.x * 256 + threadIdx.x;
  const int b = (int)(idx & 63);
  const int i = (int)(idx >> 6);
  float vals[OO];
  float m = -1e30f;
#pragma unroll
  for (int o = 0; o < OO; ++o) {
    vals[o] = blog[((size_t)o * II + i) * BB + b];
    m = fmaxf(m, vals[o]);
  }
  float sum = 0.f;
#pragma unroll
  for (int o = 0; o < OO; ++o) sum += __expf(vals[o] - m);
  sm[idx] = make_float2(m, 1.0f / sum);
}

// ---------------------------------------------------------------------------
// Merged reduce+squash: s = sum_sp partial; v = squash(s); dst = (add? dst+v : v)
// optionally vsumT[o][d][b] = dst value. One block per o.
__global__ __launch_bounds__(256) void krsq_kernel(
    const float* __restrict__ partial, float* __restrict__ dst,
    float* __restrict__ vsumT, int add) {
  const int o = blockIdx.x;
  __shared__ float ssh[DD * 65];     // padded [d][65] to dodge bank conflicts
  __shared__ float scale_sh[BB];

  // phase 1: reduce over sp; e = d*64+b (coalesced global reads)
  for (int e = threadIdx.x; e < DD * BB; e += 256) {
    float sum = 0.f;
#pragma unroll
    for (int sp = 0; sp < SPS; ++sp)
      sum += partial[((size_t)sp * OO + o) * (DD * BB) + e];
    ssh[(e >> 6) * 65 + (e & 63)] = sum;
  }
  __syncthreads();

  // phase 2: wave 0, lane b: n2 over d -> squash scale
  if (threadIdx.x < 64) {
    const int b = threadIdx.x;
    float n2 = 0.f;
#pragma unroll
    for (int d = 0; d < DD; ++d) {
      float v = ssh[d * 65 + b];
      n2 = fmaf(v, v, n2);
    }
    const float norm = sqrtf(n2);
    scale_sh[b] = n2 / ((1.0f + n2) * (norm + 1e-8f));
  }
  __syncthreads();

  // phase 3a: dst[(b*64+o)*32+d], d-fast (128B segments per 32 lanes)
  for (int e = threadIdx.x; e < DD * BB; e += 256) {
    const int d = e & 31;
    const int b = e >> 5;
    float v = ssh[d * 65 + b] * scale_sh[b];
    const size_t di = ((size_t)b * OO + o) * DD + d;
    if (add) v += dst[di];
    dst[di] = v;
  }
  // phase 3b: vsumT[(o*32+d)*64+b], b-fast (coalesced); re-derive v incl. add
  if (vsumT) {
    __syncthreads();
    for (int e = threadIdx.x; e < DD * BB; e += 256) {
      const int b = e & 63;
      const int d = e >> 6;
      const size_t di = ((size_t)b * OO + o) * DD + d;
      vsumT[((size_t)o * DD + d) * BB + b] = dst[di];
    }
  }
}

// ---------------------------------------------------------------------------
extern "C" void kernel_launch(void* const* d_in, const int* in_sizes, int n_in,
                              void* d_out, int out_size, void* d_ws, size_t ws_size,
                              hipStream_t stream) {
  const float* x = (const float*)d_in[0];
  const float* w = (const float*)d_in[1];
  float* out = (float*)d_out;

  char* ws = (char*)d_ws;
  const size_t blog_bytes = (size_t)OO * II * BB * 4;        // 18,874,368
  const size_t part_bytes = (size_t)SPS * OO * DD * BB * 4;  //  8,388,608
  const size_t yf_bytes   = (size_t)II * 2 * 64 * 8 * 2;     //  2,359,296
  const size_t so_bytes   = (size_t)BB * OO * DD * 4;        //    524,288
  const size_t sm_bytes   = (size_t)II * BB * 8;             //    589,824

  float*  blog  = (float*)ws;                      ws += blog_bytes;
  float*  part  = (float*)ws;                      ws += part_bytes;
  short*  yh    = (short*)ws;                      ws += yf_bytes;
  short*  yl    = (short*)ws;                      ws += yf_bytes;
  float*  vsum  = (float*)ws;                      ws += so_bytes;
  float*  vsumT = (float*)ws;                      ws += so_bytes;
  float2* sm    = (float2*)ws;                     ws += sm_bytes;

  dim3 gSum(SPS, OO), gBlog(SPB, OO / 4), bM(256);
  const int g_xf = (II * 64) / 256;        // 288
  const int g_sm = (II * BB) / 256;        // 288

  // prefab x B-fragments (hi/lo)
  kxfrag_kernel<<<g_xf, 256, 0, stream>>>(x, yh, yl);

  // iter 0: c uniform = 1/64 -> v0; vsum = v0 (+vsumT)
  ksum_kernel<0><<<gSum, bM, 0, stream>>>(w, yh, yl, nullptr, nullptr, part);
  krsq_kernel<<<OO, 256, 0, stream>>>(part, vsum, vsumT, 0);

  // iter 1: blog = vsum . xhat ; softmax stats ; s1 ; vsum += v1 (+vsumT)
  kblog_kernel<<<gBlog, bM, 0, stream>>>(w, yh, yl, vsumT, blog);
  kdenom_kernel<<<g_sm, 256, 0, stream>>>(blog, sm);
  ksum_kernel<1><<<gSum, bM, 0, stream>>>(w, yh, yl, blog, sm, part);
  krsq_kernel<<<OO, 256, 0, stream>>>(part, vsum, vsumT, 1);

  // iter 2: blog2 = (v0+v1) . xhat ; softmax stats ; s2 ; out = squash(s2)
  kblog_kernel<<<gBlog, bM, 0, stream>>>(w, yh, yl, vsumT, blog);
  kdenom_kernel<<<g_sm, 256, 0, stream>>>(blog, sm);
  ksum_kernel<1><<<gSum, bM, 0, stream>>>(w, yh, yl, blog, sm, part);
  krsq_kernel<<<OO, 256, 0, stream>>>(part, out, nullptr, 0);
}